// Round 2
// baseline (1232.275 us; speedup 1.0000x reference)
//
#include <hip/hip_runtime.h>

#define NNODES 50000
#define NEDGES 800000
#define NREL 8
#define NRSEG (NNODES * NREL)            // 400000 segments (dst, rel)
#define KDIM 1152                        // (R+1)*128: 8 relation slots + root slot
#define SCAN_NB ((NRSEG + 1023) / 1024)  // 391

__global__ void count_kernel(const int* __restrict__ dst, const int* __restrict__ et,
                             int* __restrict__ cnt) {
    int e = blockIdx.x * blockDim.x + threadIdx.x;
    if (e < NEDGES) atomicAdd(&cnt[dst[e] * NREL + et[e]], 1);
}

__global__ void scan1(const int* __restrict__ cnt, int* __restrict__ rowptr,
                      int* __restrict__ bsum) {
    __shared__ int sh[1024];
    int tid = threadIdx.x;
    int i = blockIdx.x * 1024 + tid;
    int v = (i < NRSEG) ? cnt[i] : 0;
    sh[tid] = v;
    __syncthreads();
    for (int off = 1; off < 1024; off <<= 1) {
        int t = (tid >= off) ? sh[tid - off] : 0;
        __syncthreads();
        sh[tid] += t;
        __syncthreads();
    }
    if (i < NRSEG) rowptr[i] = sh[tid] - v;   // exclusive within block
    if (tid == 1023) bsum[blockIdx.x] = sh[1023];
}

__global__ void scan2(const int* __restrict__ bsum, int* __restrict__ boff) {
    __shared__ int sh[512];
    int tid = threadIdx.x;
    int v = (tid < SCAN_NB) ? bsum[tid] : 0;
    sh[tid] = v;
    __syncthreads();
    for (int off = 1; off < 512; off <<= 1) {
        int t = (tid >= off) ? sh[tid - off] : 0;
        __syncthreads();
        sh[tid] += t;
        __syncthreads();
    }
    if (tid < SCAN_NB) boff[tid] = sh[tid] - v;  // exclusive block offsets
}

__global__ void scan3(int* __restrict__ rowptr, const int* __restrict__ boff) {
    int i = blockIdx.x * 1024 + threadIdx.x;
    if (i < NRSEG) rowptr[i] += boff[blockIdx.x];
    else if (i == NRSEG) rowptr[NRSEG] = NEDGES;
}

__global__ void fill_kernel(const int* __restrict__ src, const int* __restrict__ dst,
                            const int* __restrict__ et, const int* __restrict__ rowptr,
                            int* __restrict__ cursor, int* __restrict__ esrc) {
    int e = blockIdx.x * blockDim.x + threadIdx.x;
    if (e < NEDGES) {
        int s = dst[e] * NREL + et[e];
        int p = atomicAdd(&cursor[s], 1);
        esrc[rowptr[s] + p] = src[e];
    }
}

// one wave (64 lanes) per (node, relation) segment; lane handles 2 of 128 dims.
// Writes the per-segment MEAN (fp32) into A[n][r*128 + d]. Empty segment -> 0.
__global__ void agg_kernel(const float* __restrict__ xin, const int* __restrict__ rowptr,
                           const int* __restrict__ esrc, float* __restrict__ A) {
    int wid = (blockIdx.x * blockDim.x + threadIdx.x) >> 6;
    int lane = threadIdx.x & 63;
    if (wid >= NRSEG) return;
    int b = rowptr[wid], e = rowptr[wid + 1];
    float inv = 1.0f / (float)((e - b) > 1 ? (e - b) : 1);
    float ax = 0.f, ay = 0.f;
    for (int i = b; i < e; ++i) {
        const float2* p = (const float2*)(xin + (size_t)esrc[i] * 128);
        float2 v = p[lane];
        ax += v.x;
        ay += v.y;
    }
    int n = wid >> 3, r = wid & 7;
    float2 o = make_float2(ax * inv, ay * inv);
    *(float2*)(A + (size_t)n * KDIM + r * 128 + lane * 2) = o;
}

// copy previous activations into the root slot A[n][1024 + d] (fp32)
__global__ void root_kernel(const float* __restrict__ xin, float* __restrict__ A) {
    int t = blockIdx.x * blockDim.x + threadIdx.x;
    if (t >= NNODES * 64) return;
    int n = t >> 6, c = t & 63;
    float2 v = ((const float2*)(xin + (size_t)n * 128))[c];
    *(float2*)(A + (size_t)n * KDIM + 1024 + c * 2) = v;
}

// C[M,H] = A[M,1152](fp32) @ [W(1024 rows); Wr(128 rows)](fp32), fp32 accumulate.
// MODE 0: fused bias + eval-BatchNorm + ReLU.  MODE 1: fused bias + sigmoid.
// BM=128, BN=64, BK=16; 256 threads; 8x4 per-thread microtile.
template <int H, int MODE>
__global__ __launch_bounds__(256) void gemm_kernel(
    const float* __restrict__ A, const float* __restrict__ W,
    const float* __restrict__ Wr, const float* __restrict__ bias,
    const float* __restrict__ g, const float* __restrict__ be,
    const float* __restrict__ rm, const float* __restrict__ rv,
    float* __restrict__ out) {
    constexpr int M = NNODES;
    __shared__ float As[16][136];  // [k][m], pad keeps 16B align + avoids conflicts
    __shared__ float Bs[16][68];   // [k][n]
    const int tid = threadIdx.x;
    const int tx = tid & 15, ty = tid >> 4;
    const int m0 = blockIdx.x * 128;
    const int n0 = blockIdx.y * 64;
    const int arow = tid >> 1;   // 0..127
    const int ahalf = tid & 1;   // which 8-wide half of the 16 k's
    int gr = m0 + arow;
    if (gr > M - 1) gr = M - 1;  // clamp (store is guarded)
    const int brow = tid >> 4;          // 0..15 (k within tile)
    const int bcol = (tid & 15) << 2;   // 0..60

    float acc[8][4];
#pragma unroll
    for (int i = 0; i < 8; ++i)
#pragma unroll
        for (int j = 0; j < 4; ++j) acc[i][j] = 0.f;

    const float* abase = A + (size_t)gr * KDIM + ahalf * 8;
    for (int k0 = 0; k0 < KDIM; k0 += 16) {
        float4 av0 = *(const float4*)(abase + k0);
        float4 av1 = *(const float4*)(abase + k0 + 4);
        const float* bsrc = (k0 < 1024) ? (W + (size_t)(k0 + brow) * H + n0 + bcol)
                                        : (Wr + (size_t)(k0 - 1024 + brow) * H + n0 + bcol);
        float4 bv = *(const float4*)bsrc;
        As[ahalf * 8 + 0][arow] = av0.x;
        As[ahalf * 8 + 1][arow] = av0.y;
        As[ahalf * 8 + 2][arow] = av0.z;
        As[ahalf * 8 + 3][arow] = av0.w;
        As[ahalf * 8 + 4][arow] = av1.x;
        As[ahalf * 8 + 5][arow] = av1.y;
        As[ahalf * 8 + 6][arow] = av1.z;
        As[ahalf * 8 + 7][arow] = av1.w;
        *(float4*)&Bs[brow][bcol] = bv;
        __syncthreads();
#pragma unroll
        for (int k = 0; k < 16; ++k) {
            float4 a0 = *(const float4*)&As[k][ty * 8];
            float4 a1 = *(const float4*)&As[k][ty * 8 + 4];
            float4 b = *(const float4*)&Bs[k][tx * 4];
            float am[8] = {a0.x, a0.y, a0.z, a0.w, a1.x, a1.y, a1.z, a1.w};
            float bn[4] = {b.x, b.y, b.z, b.w};
#pragma unroll
            for (int i = 0; i < 8; ++i)
#pragma unroll
                for (int j = 0; j < 4; ++j) acc[i][j] = fmaf(am[i], bn[j], acc[i][j]);
        }
        __syncthreads();
    }

#pragma unroll
    for (int j = 0; j < 4; ++j) {
        int col = n0 + tx * 4 + j;
        float bb = bias[col];
        float alpha, beta;
        if (MODE == 0) {
            float s = g[col] * rsqrtf(rv[col] + 1e-5f);
            alpha = s;
            beta = (bb - rm[col]) * s + be[col];
        } else {
            alpha = 1.f;
            beta = bb;
        }
#pragma unroll
        for (int i = 0; i < 8; ++i) {
            int row = m0 + ty * 8 + i;
            if (row < M) {
                float v = fmaf(acc[i][j], alpha, beta);
                v = (MODE == 0) ? fmaxf(v, 0.f) : (1.f / (1.f + __expf(-v)));
                out[(size_t)row * H + col] = v;
            }
        }
    }
}

extern "C" void kernel_launch(void* const* d_in, const int* in_sizes, int n_in,
                              void* d_out, int out_size, void* d_ws, size_t ws_size,
                              hipStream_t stream) {
    (void)in_sizes; (void)n_in; (void)out_size; (void)ws_size;
    const float* x   = (const float*)d_in[0];
    const int* ei    = (const int*)d_in[1];
    const int* et    = (const int*)d_in[2];
    const float* W1  = (const float*)d_in[3];
    const float* Wr1 = (const float*)d_in[4];
    const float* b1  = (const float*)d_in[5];
    const float* g1  = (const float*)d_in[6];
    const float* be1 = (const float*)d_in[7];
    const float* rm1 = (const float*)d_in[8];
    const float* rv1 = (const float*)d_in[9];
    const float* W2  = (const float*)d_in[10];
    const float* Wr2 = (const float*)d_in[11];
    const float* b2  = (const float*)d_in[12];
    const float* g2  = (const float*)d_in[13];
    const float* be2 = (const float*)d_in[14];
    const float* rm2 = (const float*)d_in[15];
    const float* rv2 = (const float*)d_in[16];
    const float* W3  = (const float*)d_in[17];
    const float* Wr3 = (const float*)d_in[18];
    const float* b3  = (const float*)d_in[19];
    const int* src = ei;
    const int* dst = ei + NEDGES;
    float* out = (float*)d_out;

    char* ws = (char*)d_ws;
    size_t off = 0;
    auto alloc = [&](size_t bytes) -> void* {
        off = (off + 255) & ~(size_t)255;
        void* p = ws + off;
        off += bytes;
        return p;
    };
    int* cnt    = (int*)alloc((size_t)NRSEG * 4);
    int* rowptr = (int*)alloc((size_t)(NRSEG + 1) * 4);
    int* cursor = (int*)alloc((size_t)NRSEG * 4);
    int* bsum   = (int*)alloc((size_t)SCAN_NB * 4);
    int* boff   = (int*)alloc((size_t)SCAN_NB * 4);
    int* esrc   = (int*)alloc((size_t)NEDGES * 4);
    float* Abuf = (float*)alloc((size_t)NNODES * KDIM * 4);   // 230.4 MB
    float* h    = (float*)alloc((size_t)NNODES * 128 * 4);    // 25.6 MB

    hipMemsetAsync(cnt, 0, (size_t)NRSEG * 4, stream);
    hipMemsetAsync(cursor, 0, (size_t)NRSEG * 4, stream);

    // CSR build over (dst, rel) segments — shared by all 3 layers
    count_kernel<<<(NEDGES + 255) / 256, 256, 0, stream>>>(dst, et, cnt);
    scan1<<<SCAN_NB, 1024, 0, stream>>>(cnt, rowptr, bsum);
    scan2<<<1, 512, 0, stream>>>(bsum, boff);
    scan3<<<SCAN_NB, 1024, 0, stream>>>(rowptr, boff);
    fill_kernel<<<(NEDGES + 255) / 256, 256, 0, stream>>>(src, dst, et, rowptr, cursor, esrc);

    const int AGG_BLOCKS = NRSEG / 4;                 // 4 waves/block, 1 segment/wave
    const int ROOT_BLOCKS = (NNODES * 64 + 255) / 256;
    const int MT = (NNODES + 127) / 128;              // 391

    // layer 1: RGCN(128->128) + BN + ReLU
    agg_kernel<<<AGG_BLOCKS, 256, 0, stream>>>(x, rowptr, esrc, Abuf);
    root_kernel<<<ROOT_BLOCKS, 256, 0, stream>>>(x, Abuf);
    gemm_kernel<128, 0><<<dim3(MT, 2), 256, 0, stream>>>(Abuf, W1, Wr1, b1, g1, be1, rm1, rv1, h);

    // layer 2: RGCN(128->128) + BN + ReLU
    agg_kernel<<<AGG_BLOCKS, 256, 0, stream>>>(h, rowptr, esrc, Abuf);
    root_kernel<<<ROOT_BLOCKS, 256, 0, stream>>>(h, Abuf);
    gemm_kernel<128, 0><<<dim3(MT, 2), 256, 0, stream>>>(Abuf, W2, Wr2, b2, g2, be2, rm2, rv2, h);

    // layer 3: RGCN(128->64) + sigmoid
    agg_kernel<<<AGG_BLOCKS, 256, 0, stream>>>(h, rowptr, esrc, Abuf);
    root_kernel<<<ROOT_BLOCKS, 256, 0, stream>>>(h, Abuf);
    gemm_kernel<64, 1><<<dim3(MT, 1), 256, 0, stream>>>(Abuf, W3, Wr3, b3, nullptr, nullptr, nullptr, nullptr, out);
}

// Round 3
// 897.780 us; speedup vs baseline: 1.3726x; 1.3726x over previous
//
#include <hip/hip_runtime.h>

typedef _Float16 f16;
typedef __attribute__((ext_vector_type(8))) _Float16 half8;
typedef __attribute__((ext_vector_type(2))) _Float16 half2v;
typedef __attribute__((ext_vector_type(4))) float float4v;

#define NNODES 50000
#define NEDGES 800000
#define NREL 8
#define NRSEG (NNODES * NREL)            // 400000 segments (dst, rel)
#define KDIM 1152                        // (R+1)*128: 8 relation slots + root slot
#define MPAD 50048                       // 391*128 rows allocated for A (tail rows read-only garbage)
#define SCAN_NB ((NRSEG + 1023) / 1024)  // 391

__global__ void count_kernel(const int* __restrict__ dst, const int* __restrict__ et,
                             int* __restrict__ cnt) {
    int e = blockIdx.x * blockDim.x + threadIdx.x;
    if (e < NEDGES) atomicAdd(&cnt[dst[e] * NREL + et[e]], 1);
}

__global__ void scan1(const int* __restrict__ cnt, int* __restrict__ rowptr,
                      int* __restrict__ bsum) {
    __shared__ int sh[1024];
    int tid = threadIdx.x;
    int i = blockIdx.x * 1024 + tid;
    int v = (i < NRSEG) ? cnt[i] : 0;
    sh[tid] = v;
    __syncthreads();
    for (int off = 1; off < 1024; off <<= 1) {
        int t = (tid >= off) ? sh[tid - off] : 0;
        __syncthreads();
        sh[tid] += t;
        __syncthreads();
    }
    if (i < NRSEG) rowptr[i] = sh[tid] - v;
    if (tid == 1023) bsum[blockIdx.x] = sh[1023];
}

__global__ void scan2(const int* __restrict__ bsum, int* __restrict__ boff) {
    __shared__ int sh[512];
    int tid = threadIdx.x;
    int v = (tid < SCAN_NB) ? bsum[tid] : 0;
    sh[tid] = v;
    __syncthreads();
    for (int off = 1; off < 512; off <<= 1) {
        int t = (tid >= off) ? sh[tid - off] : 0;
        __syncthreads();
        sh[tid] += t;
        __syncthreads();
    }
    if (tid < SCAN_NB) boff[tid] = sh[tid] - v;
}

__global__ void scan3(int* __restrict__ rowptr, const int* __restrict__ boff) {
    int i = blockIdx.x * 1024 + threadIdx.x;
    if (i < NRSEG) rowptr[i] += boff[blockIdx.x];
    else if (i == NRSEG) rowptr[NRSEG] = NEDGES;
}

__global__ void fill_kernel(const int* __restrict__ src, const int* __restrict__ dst,
                            const int* __restrict__ et, const int* __restrict__ rowptr,
                            int* __restrict__ cursor, int* __restrict__ esrc) {
    int e = blockIdx.x * blockDim.x + threadIdx.x;
    if (e < NEDGES) {
        int s = dst[e] * NREL + et[e];
        int p = atomicAdd(&cursor[s], 1);
        esrc[rowptr[s] + p] = src[e];
    }
}

// fp32 [N,128] -> fp16 [N,128]
__global__ void cvt_x(const float* __restrict__ x, f16* __restrict__ x16) {
    int t = blockIdx.x * blockDim.x + threadIdx.x;
    if (t >= NNODES * 64) return;
    float2 v = ((const float2*)x)[t];
    half2v o = {(f16)v.x, (f16)v.y};
    ((half2v*)x16)[t] = o;
}

// Bt[h][k] = fp16( k<1024 ? W[k][h] : Wr[k-1024][h] )
__global__ void prep_w(const float* __restrict__ W, const float* __restrict__ Wr,
                       f16* __restrict__ Bt, int H) {
    int idx = blockIdx.x * blockDim.x + threadIdx.x;
    if (idx >= H * KDIM) return;
    int h = idx / KDIM, k = idx - h * KDIM;
    float v = (k < 1024) ? W[(size_t)k * H + h] : Wr[(size_t)(k - 1024) * H + h];
    Bt[idx] = (f16)v;
}

// one wave per (node, relation) segment; fp32 accumulate of fp16 inputs, fp16 mean out.
__global__ void agg16(const f16* __restrict__ xin, const int* __restrict__ rowptr,
                      const int* __restrict__ esrc, f16* __restrict__ A) {
    int wid = (blockIdx.x * blockDim.x + threadIdx.x) >> 6;
    int lane = threadIdx.x & 63;
    if (wid >= NRSEG) return;
    int b = rowptr[wid], e = rowptr[wid + 1];
    float inv = 1.0f / (float)((e - b) > 1 ? (e - b) : 1);
    float ax = 0.f, ay = 0.f;
    for (int i = b; i < e; ++i) {
        half2v v = ((const half2v*)(xin + (size_t)esrc[i] * 128))[lane];
        ax += (float)v.x;
        ay += (float)v.y;
    }
    int n = wid >> 3, r = wid & 7;
    half2v o = {(f16)(ax * inv), (f16)(ay * inv)};
    *(half2v*)(A + (size_t)n * KDIM + r * 128 + lane * 2) = o;
}

// copy activations (fp16 [N,128]) into root slot A[n][1024..1152)
__global__ void root16(const f16* __restrict__ xin, f16* __restrict__ A) {
    int t = blockIdx.x * blockDim.x + threadIdx.x;
    if (t >= NNODES * 64) return;
    int n = t >> 6, c = t & 63;
    half2v v = ((const half2v*)(xin + (size_t)n * 128))[c];
    *(half2v*)(A + (size_t)n * KDIM + 1024 + c * 2) = v;
}

// C[M,H] = A[M,1152](fp16) @ Bt^T (fp16), fp32 MFMA accumulate.
// MODE 0: bias+BN+ReLU -> fp16 h.   MODE 1: bias+sigmoid -> fp32 out.
// BM=128, BN=64, BK=64; 256 threads = 4 waves; wave w: rows [32w,32w+32), 2x4 16x16 tiles.
template <int H, int MODE>
__global__ __launch_bounds__(256) void gemm16(
    const f16* __restrict__ A, const f16* __restrict__ Bt,
    const float* __restrict__ bias, const float* __restrict__ g,
    const float* __restrict__ be, const float* __restrict__ rm,
    const float* __restrict__ rv, f16* __restrict__ hout, float* __restrict__ fout) {
    __shared__ f16 As[128][72];  // +8 f16 pad -> 2-way bank aliasing (free)
    __shared__ f16 Bs[64][72];
    const int tid = threadIdx.x;
    const int wave = tid >> 6, lane = tid & 63;
    const int l15 = lane & 15, quad = lane >> 4;
    const int m0 = blockIdx.x * 128;
    const int n0 = blockIdx.y * 64;
    const int srow = tid >> 3;           // 0..31 staging row
    const int soff = (tid & 7) * 8;      // 0..56 (f16 units, 16B chunks)

    float4v acc[2][4];
#pragma unroll
    for (int i = 0; i < 2; ++i)
#pragma unroll
        for (int j = 0; j < 4; ++j) acc[i][j] = (float4v){0.f, 0.f, 0.f, 0.f};

    const f16* Abase = A + (size_t)(m0 + srow) * KDIM + soff;
    const f16* Bbase = Bt + (size_t)(n0 + srow) * KDIM + soff;

    for (int k0 = 0; k0 < KDIM; k0 += 64) {
        uint4 av[4], bv[2];
#pragma unroll
        for (int p = 0; p < 4; ++p)
            av[p] = *(const uint4*)(Abase + (size_t)p * 32 * KDIM + k0);
#pragma unroll
        for (int p = 0; p < 2; ++p)
            bv[p] = *(const uint4*)(Bbase + (size_t)p * 32 * KDIM + k0);
        __syncthreads();  // prev-iter LDS reads done
#pragma unroll
        for (int p = 0; p < 4; ++p) *(uint4*)&As[srow + p * 32][soff] = av[p];
#pragma unroll
        for (int p = 0; p < 2; ++p) *(uint4*)&Bs[srow + p * 32][soff] = bv[p];
        __syncthreads();  // staging visible
#pragma unroll
        for (int ks = 0; ks < 2; ++ks) {
            half8 af[2], bf[4];
#pragma unroll
            for (int mt = 0; mt < 2; ++mt)
                af[mt] = *(const half8*)&As[wave * 32 + mt * 16 + l15][ks * 32 + quad * 8];
#pragma unroll
            for (int nt = 0; nt < 4; ++nt)
                bf[nt] = *(const half8*)&Bs[nt * 16 + l15][ks * 32 + quad * 8];
#pragma unroll
            for (int mt = 0; mt < 2; ++mt)
#pragma unroll
                for (int nt = 0; nt < 4; ++nt)
                    acc[mt][nt] = __builtin_amdgcn_mfma_f32_16x16x32_f16(
                        af[mt], bf[nt], acc[mt][nt], 0, 0, 0);
        }
    }

#pragma unroll
    for (int nt = 0; nt < 4; ++nt) {
        int col = n0 + nt * 16 + l15;
        float alpha, beta;
        if (MODE == 0) {
            float s = g[col] * rsqrtf(rv[col] + 1e-5f);
            alpha = s;
            beta = (bias[col] - rm[col]) * s + be[col];
        } else {
            alpha = 1.f;
            beta = bias[col];
        }
#pragma unroll
        for (int mt = 0; mt < 2; ++mt)
#pragma unroll
            for (int r = 0; r < 4; ++r) {
                int row = m0 + wave * 32 + mt * 16 + quad * 4 + r;
                if (row < NNODES) {
                    float v = fmaf(acc[mt][nt][r], alpha, beta);
                    if (MODE == 0) {
                        v = fmaxf(v, 0.f);
                        hout[(size_t)row * H + col] = (f16)v;
                    } else {
                        fout[(size_t)row * H + col] = 1.f / (1.f + __expf(-v));
                    }
                }
            }
    }
}

extern "C" void kernel_launch(void* const* d_in, const int* in_sizes, int n_in,
                              void* d_out, int out_size, void* d_ws, size_t ws_size,
                              hipStream_t stream) {
    (void)in_sizes; (void)n_in; (void)out_size; (void)ws_size;
    const float* x   = (const float*)d_in[0];
    const int* ei    = (const int*)d_in[1];
    const int* et    = (const int*)d_in[2];
    const float* W1  = (const float*)d_in[3];
    const float* Wr1 = (const float*)d_in[4];
    const float* b1  = (const float*)d_in[5];
    const float* g1  = (const float*)d_in[6];
    const float* be1 = (const float*)d_in[7];
    const float* rm1 = (const float*)d_in[8];
    const float* rv1 = (const float*)d_in[9];
    const float* W2  = (const float*)d_in[10];
    const float* Wr2 = (const float*)d_in[11];
    const float* b2  = (const float*)d_in[12];
    const float* g2  = (const float*)d_in[13];
    const float* be2 = (const float*)d_in[14];
    const float* rm2 = (const float*)d_in[15];
    const float* rv2 = (const float*)d_in[16];
    const float* W3  = (const float*)d_in[17];
    const float* Wr3 = (const float*)d_in[18];
    const float* b3  = (const float*)d_in[19];
    const int* src = ei;
    const int* dst = ei + NEDGES;
    float* out = (float*)d_out;

    char* ws = (char*)d_ws;
    size_t off = 0;
    auto alloc = [&](size_t bytes) -> void* {
        off = (off + 255) & ~(size_t)255;
        void* p = ws + off;
        off += bytes;
        return p;
    };
    int* cnt    = (int*)alloc((size_t)NRSEG * 4);
    int* rowptr = (int*)alloc((size_t)(NRSEG + 1) * 4);
    int* cursor = (int*)alloc((size_t)NRSEG * 4);
    int* bsum   = (int*)alloc((size_t)SCAN_NB * 4);
    int* boff   = (int*)alloc((size_t)SCAN_NB * 4);
    int* esrc   = (int*)alloc((size_t)NEDGES * 4);
    f16* Abuf   = (f16*)alloc((size_t)MPAD * KDIM * 2);     // 115.3 MB
    f16* x16    = (f16*)alloc((size_t)NNODES * 128 * 2);    // 12.8 MB
    f16* h16    = (f16*)alloc((size_t)NNODES * 128 * 2);    // 12.8 MB
    f16* Btbuf  = (f16*)alloc((size_t)128 * KDIM * 2);      // 295 KB

    hipMemsetAsync(cnt, 0, (size_t)NRSEG * 4, stream);
    hipMemsetAsync(cursor, 0, (size_t)NRSEG * 4, stream);

    // CSR build over (dst, rel) segments — shared by all 3 layers
    count_kernel<<<(NEDGES + 255) / 256, 256, 0, stream>>>(dst, et, cnt);
    scan1<<<SCAN_NB, 1024, 0, stream>>>(cnt, rowptr, bsum);
    scan2<<<1, 512, 0, stream>>>(bsum, boff);
    scan3<<<SCAN_NB, 1024, 0, stream>>>(rowptr, boff);
    fill_kernel<<<(NEDGES + 255) / 256, 256, 0, stream>>>(src, dst, et, rowptr, cursor, esrc);

    const int AGG_BLOCKS = NRSEG / 4;
    const int EL_BLOCKS = (NNODES * 64 + 255) / 256;
    const int MT = (NNODES + 127) / 128;  // 391
    const int PW128 = (128 * KDIM + 255) / 256;
    const int PW64 = (64 * KDIM + 255) / 256;

    cvt_x<<<EL_BLOCKS, 256, 0, stream>>>(x, x16);

    // layer 1: RGCN(128->128) + BN + ReLU
    prep_w<<<PW128, 256, 0, stream>>>(W1, Wr1, Btbuf, 128);
    agg16<<<AGG_BLOCKS, 256, 0, stream>>>(x16, rowptr, esrc, Abuf);
    root16<<<EL_BLOCKS, 256, 0, stream>>>(x16, Abuf);
    gemm16<128, 0><<<dim3(MT, 2), 256, 0, stream>>>(Abuf, Btbuf, b1, g1, be1, rm1, rv1, h16, nullptr);

    // layer 2: RGCN(128->128) + BN + ReLU
    prep_w<<<PW128, 256, 0, stream>>>(W2, Wr2, Btbuf, 128);
    agg16<<<AGG_BLOCKS, 256, 0, stream>>>(h16, rowptr, esrc, Abuf);
    root16<<<EL_BLOCKS, 256, 0, stream>>>(h16, Abuf);
    gemm16<128, 0><<<dim3(MT, 2), 256, 0, stream>>>(Abuf, Btbuf, b2, g2, be2, rm2, rv2, h16, nullptr);

    // layer 3: RGCN(128->64) + sigmoid
    prep_w<<<PW64, 256, 0, stream>>>(W3, Wr3, Btbuf, 64);
    agg16<<<AGG_BLOCKS, 256, 0, stream>>>(h16, rowptr, esrc, Abuf);
    root16<<<EL_BLOCKS, 256, 0, stream>>>(h16, Abuf);
    gemm16<64, 1><<<dim3(MT, 1), 256, 0, stream>>>(Abuf, Btbuf, b3, nullptr, nullptr, nullptr, nullptr, nullptr, out);
}

// Round 4
// 575.968 us; speedup vs baseline: 2.1395x; 1.5587x over previous
//
#include <hip/hip_runtime.h>

typedef _Float16 f16;
typedef __attribute__((ext_vector_type(8))) _Float16 half8;
typedef __attribute__((ext_vector_type(2))) _Float16 half2v;
typedef __attribute__((ext_vector_type(4))) float float4v;

#define NNODES 50000
#define NEDGES 800000
#define NREL 8
#define NRSEG (NNODES * NREL)            // 400000 segments (dst, rel)
#define KDIM 1152                        // (R+1)*128
#define SCAN_NB ((NRSEG + 1023) / 1024)  // 391

__global__ void count_kernel(const int* __restrict__ dst, const int* __restrict__ et,
                             int* __restrict__ cnt) {
    int e = blockIdx.x * blockDim.x + threadIdx.x;
    if (e < NEDGES) atomicAdd(&cnt[dst[e] * NREL + et[e]], 1);
}

__global__ void scan1(const int* __restrict__ cnt, int* __restrict__ rowptr,
                      int* __restrict__ bsum) {
    __shared__ int sh[1024];
    int tid = threadIdx.x;
    int i = blockIdx.x * 1024 + tid;
    int v = (i < NRSEG) ? cnt[i] : 0;
    sh[tid] = v;
    __syncthreads();
    for (int off = 1; off < 1024; off <<= 1) {
        int t = (tid >= off) ? sh[tid - off] : 0;
        __syncthreads();
        sh[tid] += t;
        __syncthreads();
    }
    if (i < NRSEG) rowptr[i] = sh[tid] - v;
    if (tid == 1023) bsum[blockIdx.x] = sh[1023];
}

__global__ void scan2(const int* __restrict__ bsum, int* __restrict__ boff) {
    __shared__ int sh[512];
    int tid = threadIdx.x;
    int v = (tid < SCAN_NB) ? bsum[tid] : 0;
    sh[tid] = v;
    __syncthreads();
    for (int off = 1; off < 512; off <<= 1) {
        int t = (tid >= off) ? sh[tid - off] : 0;
        __syncthreads();
        sh[tid] += t;
        __syncthreads();
    }
    if (tid < SCAN_NB) boff[tid] = sh[tid] - v;
}

__global__ void scan3(int* __restrict__ rowptr, const int* __restrict__ boff) {
    int i = blockIdx.x * 1024 + threadIdx.x;
    if (i < NRSEG) rowptr[i] += boff[blockIdx.x];
    else if (i == NRSEG) rowptr[NRSEG] = NEDGES;
}

__global__ void fill_kernel(const int* __restrict__ src, const int* __restrict__ dst,
                            const int* __restrict__ et, const int* __restrict__ rowptr,
                            int* __restrict__ cursor, int* __restrict__ esrc) {
    int e = blockIdx.x * blockDim.x + threadIdx.x;
    if (e < NEDGES) {
        int s = dst[e] * NREL + et[e];
        int p = atomicAdd(&cursor[s], 1);
        esrc[rowptr[s] + p] = src[e];
    }
}

// fp32 [N,128] -> fp16 [N,128]
__global__ void cvt_x(const float* __restrict__ x, f16* __restrict__ x16) {
    int t = blockIdx.x * blockDim.x + threadIdx.x;
    if (t >= NNODES * 64) return;
    float2 v = ((const float2*)x)[t];
    half2v o = {(f16)v.x, (f16)v.y};
    ((half2v*)x16)[t] = o;
}

// Bt[h][k] = fp16( k<1024 ? W[k][h] : Wr[k-1024][h] )
__global__ void prep_w(const float* __restrict__ W, const float* __restrict__ Wr,
                       f16* __restrict__ Bt, int H) {
    int idx = blockIdx.x * blockDim.x + threadIdx.x;
    if (idx >= H * KDIM) return;
    int h = idx / KDIM, k = idx - h * KDIM;
    float v = (k < 1024) ? W[(size_t)k * H + h] : Wr[(size_t)(k - 1024) * H + h];
    Bt[idx] = (f16)v;
}

// Fused RGCN layer: per 128-node tile, for each of 9 K-slots (8 relations + root)
// build the segment-mean tile in LDS (XOR-swizzled 16B granules) and MFMA against
// the staged weight slice. A matrix is never materialized in HBM.
// MODE 0: bias+BN+ReLU -> fp16 hout.  MODE 1: bias+sigmoid -> fp32 fout.
template <int H, int MODE>
__global__ __launch_bounds__(256, 2) void fused_layer(
    const f16* __restrict__ act, const f16* __restrict__ Bt,
    const int* __restrict__ rowptr, const int* __restrict__ esrc,
    const float* __restrict__ bias, const float* __restrict__ g,
    const float* __restrict__ be, const float* __restrict__ rm,
    const float* __restrict__ rv, f16* __restrict__ hout, float* __restrict__ fout) {
    constexpr int NT = H / 16;               // 8 or 4 col tiles per wave
    constexpr int GPT = (H * 16) / 256;      // weight granules per thread (8 or 4)
    constexpr int TPC = 16 / GPT;            // threads per weight col (2 or 4)
    __shared__ f16 Ms[128][128];             // mean tile, swizzled granules (32 KB)
    __shared__ f16 Ws[H][128];               // weight slice, swizzled (32/16 KB)
    const int tid = threadIdx.x;
    const int wave = tid >> 6, lane = tid & 63;
    const int l15 = lane & 15, quad = lane >> 4;
    const int m0 = blockIdx.x * 128;

    float4v acc[2][NT];
#pragma unroll
    for (int i = 0; i < 2; ++i)
#pragma unroll
        for (int j = 0; j < NT; ++j) acc[i][j] = (float4v){0.f, 0.f, 0.f, 0.f};

    for (int r = 0; r < 9; ++r) {
        __syncthreads();  // previous MFMA LDS reads complete
        // ---- stage weight slice r: Ws[col][k], 16B granules XOR-swizzled by col ----
        {
            int col = tid / TPC;
            int gb = (tid % TPC) * GPT;
            const f16* wp = Bt + (size_t)col * KDIM + r * 128 + gb * 8;
#pragma unroll
            for (int gg = 0; gg < GPT; ++gg) {
                half8 v = *(const half8*)(wp + gg * 8);
                *(half8*)&Ws[col][((gb + gg) ^ (col & 7)) * 8] = v;
            }
        }
        // ---- build Ms tile: 512 tasks = 128 segments x 4 dim-quarters ----
        if (r < 8) {
#pragma unroll
            for (int pass = 0; pass < 2; ++pass) {
                int task = tid + pass * 256;
                int i = task & 127;
                int part = (task >> 7) * 32;  // dim quarter
                int node = m0 + i;
                node = node < NNODES ? node : NNODES - 1;
                int s = node * NREL + r;
                int b = rowptr[s], e = rowptr[s + 1];
                float inv = (e - b) > 1 ? 1.f / (float)(e - b) : 1.f;
                float c[32];
#pragma unroll
                for (int t = 0; t < 32; ++t) c[t] = 0.f;
                for (int j = b; j < e; ++j) {
                    const half8* rp = (const half8*)(act + (size_t)esrc[j] * 128 + part);
                    half8 v0 = rp[0], v1 = rp[1], v2 = rp[2], v3 = rp[3];
#pragma unroll
                    for (int t = 0; t < 8; ++t) {
                        c[t] += (float)v0[t];
                        c[8 + t] += (float)v1[t];
                        c[16 + t] += (float)v2[t];
                        c[24 + t] += (float)v3[t];
                    }
                }
                int g0 = part >> 3;
#pragma unroll
                for (int gg = 0; gg < 4; ++gg) {
                    half8 o;
#pragma unroll
                    for (int t = 0; t < 8; ++t) o[t] = (f16)(c[gg * 8 + t] * inv);
                    *(half8*)&Ms[i][((g0 + gg) ^ (i & 7)) * 8] = o;
                }
            }
        } else {  // root slot: copy activation row
#pragma unroll
            for (int pass = 0; pass < 2; ++pass) {
                int task = tid + pass * 256;
                int i = task & 127;
                int part = (task >> 7) * 32;
                int node = m0 + i;
                node = node < NNODES ? node : NNODES - 1;
                const half8* rp = (const half8*)(act + (size_t)node * 128 + part);
                int g0 = part >> 3;
#pragma unroll
                for (int gg = 0; gg < 4; ++gg)
                    *(half8*)&Ms[i][((g0 + gg) ^ (i & 7)) * 8] = rp[gg];
            }
        }
        __syncthreads();
        // ---- MFMA over this K=128 slot ----
#pragma unroll
        for (int ks = 0; ks < 4; ++ks) {
            int gi = ks * 4 + quad;  // k granule index 0..15
            half8 af[2], bf[NT];
#pragma unroll
            for (int mt = 0; mt < 2; ++mt) {
                int row = wave * 32 + mt * 16 + l15;
                af[mt] = *(const half8*)&Ms[row][(gi ^ (row & 7)) * 8];
            }
#pragma unroll
            for (int nt = 0; nt < NT; ++nt) {
                int colb = nt * 16 + l15;
                bf[nt] = *(const half8*)&Ws[colb][(gi ^ (colb & 7)) * 8];
            }
#pragma unroll
            for (int mt = 0; mt < 2; ++mt)
#pragma unroll
                for (int nt = 0; nt < NT; ++nt)
                    acc[mt][nt] = __builtin_amdgcn_mfma_f32_16x16x32_f16(
                        af[mt], bf[nt], acc[mt][nt], 0, 0, 0);
        }
    }

    // ---- epilogue ----
#pragma unroll
    for (int nt = 0; nt < NT; ++nt) {
        int col = nt * 16 + l15;
        float alpha, beta;
        if (MODE == 0) {
            float s = g[col] * rsqrtf(rv[col] + 1e-5f);
            alpha = s;
            beta = (bias[col] - rm[col]) * s + be[col];
        } else {
            alpha = 1.f;
            beta = bias[col];
        }
#pragma unroll
        for (int mt = 0; mt < 2; ++mt)
#pragma unroll
            for (int rg = 0; rg < 4; ++rg) {
                int row = m0 + wave * 32 + mt * 16 + quad * 4 + rg;
                if (row < NNODES) {
                    float v = fmaf(acc[mt][nt][rg], alpha, beta);
                    if (MODE == 0) {
                        hout[(size_t)row * H + col] = (f16)fmaxf(v, 0.f);
                    } else {
                        fout[(size_t)row * H + col] = 1.f / (1.f + __expf(-v));
                    }
                }
            }
    }
}

extern "C" void kernel_launch(void* const* d_in, const int* in_sizes, int n_in,
                              void* d_out, int out_size, void* d_ws, size_t ws_size,
                              hipStream_t stream) {
    (void)in_sizes; (void)n_in; (void)out_size; (void)ws_size;
    const float* x   = (const float*)d_in[0];
    const int* ei    = (const int*)d_in[1];
    const int* et    = (const int*)d_in[2];
    const float* W1  = (const float*)d_in[3];
    const float* Wr1 = (const float*)d_in[4];
    const float* b1  = (const float*)d_in[5];
    const float* g1  = (const float*)d_in[6];
    const float* be1 = (const float*)d_in[7];
    const float* rm1 = (const float*)d_in[8];
    const float* rv1 = (const float*)d_in[9];
    const float* W2  = (const float*)d_in[10];
    const float* Wr2 = (const float*)d_in[11];
    const float* b2  = (const float*)d_in[12];
    const float* g2  = (const float*)d_in[13];
    const float* be2 = (const float*)d_in[14];
    const float* rm2 = (const float*)d_in[15];
    const float* rv2 = (const float*)d_in[16];
    const float* W3  = (const float*)d_in[17];
    const float* Wr3 = (const float*)d_in[18];
    const float* b3  = (const float*)d_in[19];
    const int* src = ei;
    const int* dst = ei + NEDGES;
    float* out = (float*)d_out;

    char* ws = (char*)d_ws;
    size_t off = 0;
    auto alloc = [&](size_t bytes) -> void* {
        off = (off + 255) & ~(size_t)255;
        void* p = ws + off;
        off += bytes;
        return p;
    };
    int* cnt    = (int*)alloc((size_t)NRSEG * 4);
    int* rowptr = (int*)alloc((size_t)(NRSEG + 1) * 4);
    int* cursor = (int*)alloc((size_t)NRSEG * 4);
    int* bsum   = (int*)alloc((size_t)SCAN_NB * 4);
    int* boff   = (int*)alloc((size_t)SCAN_NB * 4);
    int* esrc   = (int*)alloc((size_t)NEDGES * 4);
    f16* x16    = (f16*)alloc((size_t)NNODES * 128 * 2);
    f16* ha     = (f16*)alloc((size_t)NNODES * 128 * 2);
    f16* hb     = (f16*)alloc((size_t)NNODES * 128 * 2);
    f16* Bt1    = (f16*)alloc((size_t)128 * KDIM * 2);
    f16* Bt2    = (f16*)alloc((size_t)128 * KDIM * 2);
    f16* Bt3    = (f16*)alloc((size_t)64 * KDIM * 2);

    hipMemsetAsync(cnt, 0, (size_t)NRSEG * 4, stream);
    hipMemsetAsync(cursor, 0, (size_t)NRSEG * 4, stream);

    // CSR build over (dst, rel) segments — shared by all 3 layers
    count_kernel<<<(NEDGES + 255) / 256, 256, 0, stream>>>(dst, et, cnt);
    scan1<<<SCAN_NB, 1024, 0, stream>>>(cnt, rowptr, bsum);
    scan2<<<1, 512, 0, stream>>>(bsum, boff);
    scan3<<<SCAN_NB, 1024, 0, stream>>>(rowptr, boff);
    fill_kernel<<<(NEDGES + 255) / 256, 256, 0, stream>>>(src, dst, et, rowptr, cursor, esrc);

    const int EL_BLOCKS = (NNODES * 64 + 255) / 256;
    const int MT = (NNODES + 127) / 128;  // 391
    cvt_x<<<EL_BLOCKS, 256, 0, stream>>>(x, x16);
    prep_w<<<(128 * KDIM + 255) / 256, 256, 0, stream>>>(W1, Wr1, Bt1, 128);
    prep_w<<<(128 * KDIM + 255) / 256, 256, 0, stream>>>(W2, Wr2, Bt2, 128);
    prep_w<<<(64 * KDIM + 255) / 256, 256, 0, stream>>>(W3, Wr3, Bt3, 64);

    fused_layer<128, 0><<<MT, 256, 0, stream>>>(x16, Bt1, rowptr, esrc,
                                                b1, g1, be1, rm1, rv1, ha, nullptr);
    fused_layer<128, 0><<<MT, 256, 0, stream>>>(ha, Bt2, rowptr, esrc,
                                                b2, g2, be2, rm2, rv2, hb, nullptr);
    fused_layer<64, 1><<<MT, 256, 0, stream>>>(hb, Bt3, rowptr, esrc,
                                               b3, nullptr, nullptr, nullptr, nullptr,
                                               nullptr, out);
}